// Round 10
// baseline (365.488 us; speedup 1.0000x reference)
//
#include <hip/hip_runtime.h>
#include <math.h>

#define DMODEL 1024
#define SEQ    2048
#define NELEM  4194304   // B*S*d
#define N4     (NELEM / 4)

typedef __attribute__((ext_vector_type(8))) short short8;    // 8 bf16 (4 VGPRs)
typedef __attribute__((ext_vector_type(4))) short short4v;   // 4 bf16 (2 VGPRs)
typedef __attribute__((ext_vector_type(4))) float f32x4;     // C/D frag

#if __has_builtin(__builtin_amdgcn_exp2f)
#define EXP2(x) __builtin_amdgcn_exp2f(x)   // raw v_exp_f32, <=2 ulp
#else
#define EXP2(x) exp2f(x)
#endif

// async 16B global->LDS (DMA): LDS dest = wave-uniform base + lane*16
__device__ __forceinline__ void gl2lds16(const unsigned short* g, unsigned short* l) {
    __builtin_amdgcn_global_load_lds(
        (const __attribute__((address_space(1))) unsigned int*)g,
        (__attribute__((address_space(3))) unsigned int*)l,
        16, 0, 0);
}

// ---------- numeric helpers (bit-exact vs numpy reference) ----------
__device__ __forceinline__ float fq(float x, float m) {
    float t = x / m * 128.0f;      // correctly-rounded div, exact *128
    float r = rintf(t);            // half-even == np.round
    float q = r * 0.0078125f * m;
    return (m > 0.0f) ? q : x;
}
__device__ __forceinline__ unsigned short f2bf(float f) {   // RNE float->bf16 bits
    unsigned int u = __float_as_uint(f);
    u += 0x7FFFu + ((u >> 16) & 1u);
    return (unsigned short)(u >> 16);
}
__device__ __forceinline__ float bf2f(unsigned short h) {
    return __uint_as_float(((unsigned int)h) << 16);
}
// bf16 bits of rintf(x/m*128): integer in [-128,128] -> exact (truncate works)
__device__ __forceinline__ unsigned short qint(float x, float m) {
    float i = rintf(x / m * 128.0f);
    return (unsigned short)(__float_as_uint(i) >> 16);
}

__device__ __forceinline__ void block_max_atomic(float v, float* red, unsigned int* slot) {
    const int t = threadIdx.x;
    red[t] = v;
    __syncthreads();
    #pragma unroll
    for (int s = 128; s > 0; s >>= 1) {
        if (t < s) red[t] = fmaxf(red[t], red[t + s]);
        __syncthreads();
    }
    if (t == 0) atomicMax(slot, __float_as_uint(red[0]));   // bits monotone for >=0
}

// barrier-free: 6-shuffle wave max + one atomic per wave
__device__ __forceinline__ void wave_max_atomic(float v, int lane, unsigned int* slot) {
    v = fmaxf(v, __shfl_xor(v, 1));
    v = fmaxf(v, __shfl_xor(v, 2));
    v = fmaxf(v, __shfl_xor(v, 4));
    v = fmaxf(v, __shfl_xor(v, 8));
    v = fmaxf(v, __shfl_xor(v, 16));
    v = fmaxf(v, __shfl_xor(v, 32));
    if (lane == 0) atomicMax(slot, __float_as_uint(v));
}

// ---------- elementwise kernels ----------
// Fused: z=0..3 split W into bf16 hi/lo; z=4 absmax(x)
__global__ __launch_bounds__(256) void wsplit_absmax(
    const float* __restrict__ W0, const float* __restrict__ W1,
    const float* __restrict__ W2, const float* __restrict__ W3,
    unsigned short* __restrict__ H0, unsigned short* __restrict__ L0,
    unsigned short* __restrict__ H1, unsigned short* __restrict__ L1,
    unsigned short* __restrict__ H2, unsigned short* __restrict__ L2,
    unsigned short* __restrict__ H3, unsigned short* __restrict__ L3,
    const float* __restrict__ x, int n4, unsigned int* __restrict__ slot) {
    __shared__ float red[256];
    const int z = blockIdx.y;
    if (z == 4) {
        float m = 0.0f;
        const float4* x4 = (const float4*)x;
        for (int i = blockIdx.x * 256 + threadIdx.x; i < n4; i += gridDim.x * 256) {
            float4 v = x4[i];
            m = fmaxf(m, fmaxf(fmaxf(fabsf(v.x), fabsf(v.y)), fmaxf(fabsf(v.z), fabsf(v.w))));
        }
        block_max_atomic(m, red, slot);
        return;
    }
    const float* W = (z == 0) ? W0 : (z == 1) ? W1 : (z == 2) ? W2 : W3;
    unsigned short* H = (z == 0) ? H0 : (z == 1) ? H1 : (z == 2) ? H2 : H3;
    unsigned short* L = (z == 0) ? L0 : (z == 1) ? L1 : (z == 2) ? L2 : L3;
    const int i = blockIdx.x * 256 + threadIdx.x;   // grid.x*256 == 1024*1024/4
    float4 w = ((const float4*)W)[i];
    ushort4 h, l;
    h.x = f2bf(w.x); l.x = f2bf(w.x - bf2f(h.x));
    h.y = f2bf(w.y); l.y = f2bf(w.y - bf2f(h.y));
    h.z = f2bf(w.z); l.z = f2bf(w.z - bf2f(h.z));
    h.w = f2bf(w.w); l.w = f2bf(w.w - bf2f(h.w));
    ((ushort4*)H)[i] = h;
    ((ushort4*)L)[i] = l;
}

__global__ __launch_bounds__(256) void quant_int_kernel(const float* __restrict__ src,
                                                        unsigned short* __restrict__ dst,
                                                        const unsigned int* __restrict__ slot,
                                                        int n4) {
    const float m = __uint_as_float(*slot);
    const float4* s4 = (const float4*)src;
    for (int i = blockIdx.x * 256 + threadIdx.x; i < n4; i += gridDim.x * 256) {
        float4 v = s4[i];
        ushort4 o;
        o.x = qint(v.x, m); o.y = qint(v.y, m); o.z = qint(v.z, m); o.w = qint(v.w, m);
        ((ushort4*)dst)[i] = o;
    }
}

__global__ __launch_bounds__(256) void quant_out_kernel(float* __restrict__ Y,
                                                        const unsigned int* __restrict__ slot,
                                                        int n4) {
    const float m = __uint_as_float(*slot);
    float4* y4 = (float4*)Y;
    for (int i = blockIdx.x * 256 + threadIdx.x; i < n4; i += gridDim.x * 256) {
        float4 v = y4[i];
        v.x = fq(v.x, m); v.y = fq(v.y, m); v.z = fq(v.z, m); v.w = fq(v.w, m);
        y4[i] = v;
    }
}

// Fused post-QKV pass: y=0 quantize K raw->int; y=1 transpose+quantize V
__global__ __launch_bounds__(256) void quantK_vtrans(
    const float* __restrict__ Kraw, unsigned short* __restrict__ Ki,
    const unsigned int* __restrict__ slotK,
    const float* __restrict__ Vraw, unsigned short* __restrict__ Vti,
    const unsigned int* __restrict__ slotV, int n4) {
    __shared__ float tile[64][65];
    if (blockIdx.y == 0) {
        const float m = __uint_as_float(*slotK);
        const float4* s4 = (const float4*)Kraw;
        for (int i = blockIdx.x * 256 + threadIdx.x; i < n4; i += gridDim.x * 256) {
            float4 v = s4[i];
            ushort4 o;
            o.x = qint(v.x, m); o.y = qint(v.y, m); o.z = qint(v.z, m); o.w = qint(v.w, m);
            ((ushort4*)Ki)[i] = o;
        }
        return;
    }
    const float mv = __uint_as_float(*slotV);
    const int t = threadIdx.x;
    const int s0 = (blockIdx.x & 31) << 6;
    const int bh = blockIdx.x >> 5;
    const int b = bh >> 4, h = bh & 15;
    const int rr = t >> 4;            // 0..15
    const int cc = (t & 15) << 2;     // 0..60
    #pragma unroll
    for (int rep = 0; rep < 4; rep++) {
        int srow = rep * 16 + rr;
        float4 v = *(const float4*)&Vraw[(size_t)b * SEQ * DMODEL + (size_t)(s0 + srow) * DMODEL + h * 64 + cc];
        tile[srow][cc + 0] = v.x; tile[srow][cc + 1] = v.y;
        tile[srow][cc + 2] = v.z; tile[srow][cc + 3] = v.w;
    }
    __syncthreads();
    #pragma unroll
    for (int rep = 0; rep < 4; rep++) {
        int drow = rep * 16 + rr;
        ushort4 o;
        o.x = qint(tile[cc + 0][drow], mv);
        o.y = qint(tile[cc + 1][drow], mv);
        o.z = qint(tile[cc + 2][drow], mv);
        o.w = qint(tile[cc + 3][drow], mv);
        *(ushort4*)&Vti[(size_t)bh * 64 * SEQ + (size_t)drow * SEQ + s0 + cc] = o;
    }
}

// ---------- MFMA GEMM: y = (mA/128) * (iA @ (Whi+Wlo)^T) + b ----------
// BM=128, BN=64, BK=32 x2 per barrier-pair (two ping/pong LDS tile-sets staged
// per __syncthreads pair -> HALF the barrier-drain events of round 9).
// m97 recipe: global_load_lds width=16 into UNPADDED row-major LDS (64B rows),
// ds_read_b128 frags. Grid m-fastest: consecutive blocks share W-tiles (L2-hot).
template<int BN>
__global__ __launch_bounds__(256) void gemm_mfma(
    const unsigned short* __restrict__ Ai, const unsigned int* __restrict__ mSlot,
    const unsigned short* __restrict__ Wh0, const unsigned short* __restrict__ Wl0,
    const float* __restrict__ b0, float* __restrict__ O0, unsigned int* __restrict__ s0,
    const unsigned short* __restrict__ Wh1, const unsigned short* __restrict__ Wl1,
    const float* __restrict__ b1, float* __restrict__ O1, unsigned int* __restrict__ s1,
    const unsigned short* __restrict__ Wh2, const unsigned short* __restrict__ Wl2,
    const float* __restrict__ b2, float* __restrict__ O2, unsigned int* __restrict__ s2) {
    constexpr int NI = BN / 32;
    __shared__ __align__(16) unsigned short As[2][128 * 32];
    __shared__ __align__(16) unsigned short Bh[2][BN * 32];
    __shared__ __align__(16) unsigned short Bl[2][BN * 32];

    const int z = blockIdx.z;
    const unsigned short* Wh = (z == 0) ? Wh0 : (z == 1) ? Wh1 : Wh2;
    const unsigned short* Wl = (z == 0) ? Wl0 : (z == 1) ? Wl1 : Wl2;
    const float* bias = (z == 0) ? b0 : (z == 1) ? b1 : b2;
    float* O = (z == 0) ? O0 : (z == 1) ? O1 : O2;
    unsigned int* slotOut = (z == 0) ? s0 : (z == 1) ? s1 : s2;

    const float mA = __uint_as_float(*mSlot);
    const int t = threadIdx.x;
    const int lane = t & 63, w = t >> 6;
    const int ml = lane & 15, qd = lane >> 4;
    const int wm = w & 1, wn = w >> 1;
    const int m0 = blockIdx.x << 7;        // m is grid-x (fastest): W stays L2-hot
    const int n0 = blockIdx.y * BN;

    const int lr = lane >> 2;           // 0..15
    const int lc = (lane & 3) << 3;     // ushort col 0,8,16,24
    const unsigned short* Asrc = Ai + (size_t)(m0 + w * 32 + lr) * DMODEL + lc;
    const unsigned short* Hsrc = Wh + (size_t)(n0 + w * (BN / 4) + lr) * DMODEL + lc;
    const unsigned short* Lsrc = Wl + (size_t)(n0 + w * (BN / 4) + lr) * DMODEL + lc;

    f32x4 acc[4][NI];
    #pragma unroll
    for (int mi = 0; mi < 4; mi++)
        #pragma unroll
        for (int ni = 0; ni < NI; ni++) acc[mi][ni] = (f32x4){0.f, 0.f, 0.f, 0.f};

    for (int k0 = 0; k0 < DMODEL; k0 += 64) {
        __syncthreads();                 // previous super-iter's LDS reads done
        #pragma unroll
        for (int hb = 0; hb < 2; hb++) {
            const int ko = k0 + hb * 32;
            gl2lds16(Asrc + ko,               &As[hb][(w * 32) * 32]);
            gl2lds16(Asrc + ko + 16 * DMODEL, &As[hb][(w * 32 + 16) * 32]);
            gl2lds16(Hsrc + ko, &Bh[hb][(w * (BN / 4)) * 32]);
            gl2lds16(Lsrc + ko, &Bl[hb][(w * (BN / 4)) * 32]);
        }
        __syncthreads();                 // barrier drains vmcnt -> LDS visible

        #pragma unroll
        for (int hb = 0; hb < 2; hb++) {
            short8 af[4];
            #pragma unroll
            for (int mi = 0; mi < 4; mi++)
                af[mi] = *(const short8*)&As[hb][(wm * 64 + mi * 16 + ml) * 32 + qd * 8];
            #pragma unroll
            for (int ni = 0; ni < NI; ni++) {
                short8 bh = *(const short8*)&Bh[hb][(wn * (BN / 2) + ni * 16 + ml) * 32 + qd * 8];
                short8 bl = *(const short8*)&Bl[hb][(wn * (BN / 2) + ni * 16 + ml) * 32 + qd * 8];
                #pragma unroll
                for (int mi = 0; mi < 4; mi++) {
                    acc[mi][ni] = __builtin_amdgcn_mfma_f32_16x16x32_bf16(af[mi], bh, acc[mi][ni], 0, 0, 0);
                    acc[mi][ni] = __builtin_amdgcn_mfma_f32_16x16x32_bf16(af[mi], bl, acc[mi][ni], 0, 0, 0);
                }
            }
        }
    }

    const float s = mA * 0.0078125f;
    float lmax = 0.0f;
    #pragma unroll
    for (int ni = 0; ni < NI; ni++) {
        const int col = n0 + wn * (BN / 2) + ni * 16 + ml;
        const float bc = bias[col];
        #pragma unroll
        for (int mi = 0; mi < 4; mi++) {
            #pragma unroll
            for (int r = 0; r < 4; r++) {
                int row = m0 + wm * 64 + mi * 16 + qd * 4 + r;
                float v = acc[mi][ni][r] * s + bc;
                lmax = fmaxf(lmax, fabsf(v));
                O[row * DMODEL + col] = v;
            }
        }
    }
    wave_max_atomic(lmax, lane, slotOut);
}

// ---------- MFMA flash attention: transposed S^T = K Q^T, double-buffered LDS,
// TWO q-tiles per wave (K/V A-frags + staging + barriers shared). In-lane
// softmax; P^T is ALREADY the K=16 B-operand layout -> PV shuffle-free.
__global__ __launch_bounds__(256) void attn_mfma(
    const float* __restrict__ Qraw, const unsigned short* __restrict__ Ki,
    const unsigned short* __restrict__ Vti, const unsigned int* __restrict__ slots,
    float* __restrict__ Out, unsigned int* __restrict__ moSlot) {
    __shared__ __align__(16) unsigned short Ks[2][64 * 72];   // [k][d], 2x9 KB
    __shared__ __align__(16) unsigned short Vt[2][64 * 72];   // [d][k], 2x9 KB
    union U8 { short8 v; unsigned short u[8]; };
    union U4 { short4v v; unsigned short u[4]; };

    const int t = threadIdx.x;
    const int lane = t & 63, w = t >> 6;
    const int ml = lane & 15, qd = lane >> 4;
    const int q0 = blockIdx.x << 7;           // block covers 128 q-cols
    const int bh = blockIdx.y;
    const int b = bh >> 4, h = bh & 15;
    const float mq = __uint_as_float(slots[1]);
    const float mk = __uint_as_float(slots[2]);
    const float mv = __uint_as_float(slots[3]);
    const float c2 = (mq * 0.0078125f) * (mk * 0.0078125f) * 0.125f * 1.4426950408889634f;
    const int baseQ = b * SEQ * DMODEL + h * 64;
    const int qgA = q0 + w * 32 + ml;
    const int qgB = qgA + 16;

    // Q B-frags for both tiles (quantize once from raw)
    short8 bq[2][2];
    #pragma unroll
    for (int g = 0; g < 2; g++) {
        const float* src = Qraw + baseQ + (size_t)(g ? qgB : qgA) * DMODEL + qd * 8;
        #pragma unroll
        for (int c = 0; c < 2; c++) {
            float4 v0 = *(const float4*)(src + c * 32);
            float4 v1 = *(const float4*)(src + c * 32 + 4);
            U8 tmp;
            tmp.u[0] = qint(v0.x, mq); tmp.u[1] = qint(v0.y, mq);
            tmp.u[2] = qint(v0.z, mq); tmp.u[3] = qint(v0.w, mq);
            tmp.u[4] = qint(v1.x, mq); tmp.u[5] = qint(v1.y, mq);
            tmp.u[6] = qint(v1.z, mq); tmp.u[7] = qint(v1.w, mq);
            bq[g][c] = tmp.v;
        }
    }

    f32x4 oacc[2][4];
    #pragma unroll
    for (int g = 0; g < 2; g++)
        #pragma unroll
        for (int i = 0; i < 4; i++) oacc[g][i] = (f32x4){0.f, 0.f, 0.f, 0.f};
    float mrun[2] = {-INFINITY, -INFINITY}, lrun[2] = {0.f, 0.f};

    // cooperative staging: thread t handles row sr = t>>2, 32B segment (t&3)
    const int sr = t >> 2;
    const int sc = (t & 3) << 4;            // ushort offset 0,16,32,48
    const unsigned short* kstage = Ki + baseQ + (size_t)sr * DMODEL + sc;
    const unsigned short* vstage = Vti + (size_t)bh * 64 * SEQ + (size_t)sr * SEQ + sc;

    // prologue: stage tile 0 into buffer 0
    {
        short8 a = *(const short8*)kstage;
        short8 bb = *(const short8*)(kstage + 8);
        short8 c = *(const short8*)vstage;
        short8 d = *(const short8*)(vstage + 8);
        *(short8*)&Ks[0][sr * 72 + sc] = a;
        *(short8*)&Ks[0][sr * 72 + sc + 8] = bb;
        *(short8*)&Vt[0][sr * 72 + sc] = c;
        *(short8*)&Vt[0][sr * 72 + sc + 8] = d;
    }
    __syncthreads();

    for (int it = 0; it < 32; it++) {
        const int cur = it & 1;
        // ---- prefetch next tile to registers (latency hidden under compute)
        short8 nk0, nk1, nv0, nv1;
        if (it < 31) {
            const size_t ko = (size_t)(it + 1) * 64;
            nk0 = *(const short8*)(kstage + ko * DMODEL);
            nk1 = *(const short8*)(kstage + ko * DMODEL + 8);
            nv0 = *(const short8*)(vstage + ko);
            nv1 = *(const short8*)(vstage + ko + 8);
        }

        // ---- S^T tiles for both q-groups, sharing K A-frags
        f32x4 sacc[2][4];
        #pragma unroll
        for (int tau = 0; tau < 4; tau++) {
            short8 a0 = *(const short8*)&Ks[cur][(tau * 16 + ml) * 72 + qd * 8];
            short8 a1 = *(const short8*)&Ks[cur][(tau * 16 + ml) * 72 + 32 + qd * 8];
            #pragma unroll
            for (int g = 0; g < 2; g++) {
                f32x4 z4 = (f32x4){0.f, 0.f, 0.f, 0.f};
                z4 = __builtin_amdgcn_mfma_f32_16x16x32_bf16(a0, bq[g][0], z4, 0, 0, 0);
                sacc[g][tau] = __builtin_amdgcn_mfma_f32_16x16x32_bf16(a1, bq[g][1], z4, 0, 0, 0);
            }
        }

        // ---- online softmax per tile (all 16 scores of a q-col in-lane)
        float alpha[2];
        short4v phi[2][4], plo[2][4];
        #pragma unroll
        for (int g = 0; g < 2; g++) {
            float tmax = fmaxf(fmaxf(fmaxf(sacc[g][0][0], sacc[g][0][1]), fmaxf(sacc[g][0][2], sacc[g][0][3])),
                               fmaxf(fmaxf(sacc[g][1][0], sacc[g][1][1]), fmaxf(sacc[g][1][2], sacc[g][1][3])));
            tmax = fmaxf(tmax, fmaxf(fmaxf(fmaxf(sacc[g][2][0], sacc[g][2][1]), fmaxf(sacc[g][2][2], sacc[g][2][3])),
                                     fmaxf(fmaxf(sacc[g][3][0], sacc[g][3][1]), fmaxf(sacc[g][3][2], sacc[g][3][3]))));
            tmax = fmaxf(tmax, __shfl_xor(tmax, 16));
            tmax = fmaxf(tmax, __shfl_xor(tmax, 32));
            const float mnew = fmaxf(mrun[g], tmax);
            alpha[g] = EXP2((mrun[g] - mnew) * c2);
            const float mc = mnew * c2;
            float ls = 0.0f;
            #pragma unroll
            for (int tau = 0; tau < 4; tau++) {
                U4 hh, ll;
                #pragma unroll
                for (int r = 0; r < 4; r++) {
                    float pv = EXP2(sacc[g][tau][r] * c2 - mc);
                    ls += pv;
                    unsigned int u = __float_as_uint(pv);
                    unsigned int uh = u & 0xFFFF0000u;               // trunc hi
                    hh.u[r] = (unsigned short)(u >> 16);
                    float lf = pv - __uint_as_float(uh);             // exact residual >= 0
                    ll.u[r] = (unsigned short)(__float_as_uint(lf) >> 16);  // trunc lo
                }
                phi[g][tau] = hh.v;
                plo[g][tau] = ll.v;
            }
            ls += __shfl_xor(ls, 16);
            ls += __shfl_xor(ls, 32);
            lrun[g] = lrun[g] * alpha[g] + ls;
            mrun[g] = mnew;
        }

        // ---- rescale O
        #pragma unroll
        for (int g = 0; g < 2; g++)
            #pragma unroll
            for (int i = 0; i < 4; i++) {
                oacc[g][i][0] *= alpha[g]; oacc[g][i][1] *= alpha[g];
                oacc[g][i][2] *= alpha[g]; oacc[g][i][3] *= alpha[g];
            }

        // ---- O^T += V^T P^T via K=16 MFMA; V A-frags shared across both tiles
        #pragma unroll
        for (int td = 0; td < 4; td++) {
            #pragma unroll
            for (int tau = 0; tau < 4; tau++) {
                short4v av = *(const short4v*)&Vt[cur][(td * 16 + ml) * 72 + tau * 16 + qd * 4];
                #pragma unroll
                for (int g = 0; g < 2; g++) {
                    oacc[g][td] = __builtin_amdgcn_mfma_f32_16x16x16bf16_1k(av, phi[g][tau], oacc[g][td], 0, 0, 0);
                    oacc[g][td] = __builtin_amdgcn_mfma_f32_16x16x16bf16_1k(av, plo[g][tau], oacc[g][td], 0, 0, 0);
                }
            }
        }

        // ---- write next tile into the other buffer; one barrier per iter
        if (it < 31) {
            *(short8*)&Ks[cur ^ 1][sr * 72 + sc] = nk0;
            *(short8*)&Ks[cur ^ 1][sr * 72 + sc + 8] = nk1;
            *(short8*)&Vt[cur ^ 1][sr * 72 + sc] = nv0;
            *(short8*)&Vt[cur ^ 1][sr * 72 + sc + 8] = nv1;
        }
        __syncthreads();
    }

    // ---- epilogue: O[qg][d] = oacc[td][r] * (mv/128) / lrun
    float lmax = 0.0f;
    #pragma unroll
    for (int g = 0; g < 2; g++) {
        const float inv = (mv * 0.0078125f) / lrun[g];
        const int qg = g ? qgB : qgA;
        #pragma unroll
        for (int td = 0; td < 4; td++) {
            float4 o;
            o.x = oacc[g][td][0] * inv;
            o.y = oacc[g][td][1] * inv;
            o.z = oacc[g][td][2] * inv;
            o.w = oacc[g][td][3] * inv;
            lmax = fmaxf(lmax, fmaxf(fmaxf(fabsf(o.x), fabsf(o.y)), fmaxf(fabsf(o.z), fabsf(o.w))));
            *(float4*)&Out[baseQ + (size_t)qg * DMODEL + td * 16 + qd * 4] = o;
        }
    }
    wave_max_atomic(lmax, lane, moSlot);
}

// ---------- launcher ----------
extern "C" void kernel_launch(void* const* d_in, const int* in_sizes, int n_in,
                              void* d_out, int out_size, void* d_ws, size_t ws_size,
                              hipStream_t stream) {
    const float* x  = (const float*)d_in[0];
    const float* Wq = (const float*)d_in[1];
    const float* bq = (const float*)d_in[2];
    const float* Wk = (const float*)d_in[3];
    const float* bk = (const float*)d_in[4];
    const float* Wv = (const float*)d_in[5];
    const float* bv = (const float*)d_in[6];
    const float* Wo = (const float*)d_in[7];
    const float* bo = (const float*)d_in[8];
    float* out = (float*)d_out;

    const size_t MB = 1024 * 1024;
    unsigned int* slots = (unsigned int*)d_ws;
    char* p = (char*)d_ws + 256;
    unsigned short* WqH = (unsigned short*)(p + 0 * MB);
    unsigned short* WqL = (unsigned short*)(p + 2 * MB);
    unsigned short* WkH = (unsigned short*)(p + 4 * MB);
    unsigned short* WkL = (unsigned short*)(p + 6 * MB);
    unsigned short* WvH = (unsigned short*)(p + 8 * MB);
    unsigned short* WvL = (unsigned short*)(p + 10 * MB);
    unsigned short* WoH = (unsigned short*)(p + 12 * MB);
    unsigned short* WoL = (unsigned short*)(p + 14 * MB);
    unsigned short* Xi  = (unsigned short*)(p + 16 * MB);  // 8 MB, x as int-bf16
    float* RA  = (float*)(p + 24 * MB);                    // 16 MB: Kraw -> Oi
    float* RB  = (float*)(p + 40 * MB);                    // 16 MB: Vraw -> attn-out raw
    unsigned short* Vti = (unsigned short*)(p + 56 * MB);  // 8 MB, V^T int-bf16
    unsigned short* Ki  = (unsigned short*)(p + 4 * MB);   // 8 MB, overlays Wk/Wv splits (dead)
    unsigned short* Oi  = (unsigned short*)RA;             // 8 MB, overlays Kraw (dead)
    float* Qraw = out;   // d_out doubles as 16 MB scratch for raw Q (dead before O-GEMM)

    hipMemsetAsync(d_ws, 0, 256, stream);  // zero max slots

    // fused weight-split (z=0..3) + absmax(x) (z=4)
    wsplit_absmax<<<dim3(1024, 5), 256, 0, stream>>>(Wq, Wk, Wv, Wo,
        WqH, WqL, WkH, WkL, WvH, WvL, WoH, WoL, x, N4, slots + 0);
    quant_int_kernel<<<1024, 256, 0, stream>>>(x, Xi, slots + 0, N4);

    // Fused Q/K/V projections; m-fastest grid, 1536 WGs = 6 WG/CU
    gemm_mfma<64><<<dim3(32, 16, 3), 256, 0, stream>>>(Xi, slots + 0,
        WqH, WqL, bq, Qraw, slots + 1,
        WkH, WkL, bk, RA,   slots + 2,
        WvH, WvL, bv, RB,   slots + 3);
    // fused: quantize K (y=0) + transpose-quantize V (y=1)
    quantK_vtrans<<<dim3(1024, 2), 256, 0, stream>>>(RA, Ki, slots + 2,
                                                     RB, Vti, slots + 3, N4);

    // attention: raw out into RB (over dead Vraw), slot4 = max|attn out|
    attn_mfma<<<dim3(16, 32), 256, 0, stream>>>(Qraw, Ki, Vti, slots, RB, slots + 4);
    quant_int_kernel<<<1024, 256, 0, stream>>>(RB, Oi, slots + 4, N4);

    // O projection into d_out (overwrites dead Qraw), then final fake-quant in place
    gemm_mfma<64><<<dim3(32, 16, 1), 256, 0, stream>>>(Oi, slots + 4,
        WoH, WoL, bo, out, slots + 5,
        WoH, WoL, bo, out, slots + 5,
        WoH, WoL, bo, out, slots + 5);
    quant_out_kernel<<<1024, 256, 0, stream>>>(out, slots + 5, N4);
}